// Round 3
// baseline (1192.681 us; speedup 1.0000x reference)
//
#include <hip/hip_runtime.h>

#define NN 100000
#define EE 1600000
#define HD 128
#define GG 64
#define NB 391          // ceil(NN/256)
#define BNEPS 1e-5f

// ---------------- degree histogram + dinv ----------------
__global__ void k_hist(const int* __restrict__ ei, int* __restrict__ cnt){
  int e = blockIdx.x*256 + threadIdx.x;
  if (e < EE) atomicAdd(&cnt[ei[EE + e]], 1);
}

__global__ void k_dinv(const int* __restrict__ cnt, float* __restrict__ dinv){
  int n = blockIdx.x*256 + threadIdx.x;
  if (n < NN) dinv[n] = rsqrtf(1.0f + (float)cnt[n]);
}

// ---------------- exclusive scan of degree counts ----------------
__global__ void k_scanA(const int* __restrict__ cnt, int* __restrict__ offs,
                        int* __restrict__ bsum){
  __shared__ int s[256];
  int tid = threadIdx.x;
  int n = blockIdx.x*256 + tid;
  int v = (n < NN) ? cnt[n] : 0;
  s[tid] = v; __syncthreads();
  for (int d = 1; d < 256; d <<= 1){
    int t = (tid >= d) ? s[tid-d] : 0;
    __syncthreads();
    s[tid] += t;
    __syncthreads();
  }
  if (n < NN) offs[n] = s[tid] - v;          // block-local exclusive
  if (tid == 255) bsum[blockIdx.x] = s[255]; // block total
}

__global__ void k_scanB(int* __restrict__ bsum){
  __shared__ int s[512];
  int tid = threadIdx.x;
  int v = (tid < NB) ? bsum[tid] : 0;
  s[tid] = v; __syncthreads();
  for (int d = 1; d < 512; d <<= 1){
    int t = (tid >= d) ? s[tid-d] : 0;
    __syncthreads();
    s[tid] += t;
    __syncthreads();
  }
  if (tid < NB) bsum[tid] = s[tid] - v;      // exclusive block bases
}

__global__ void k_scanC(int* __restrict__ offs, const int* __restrict__ bsum){
  int n = blockIdx.x*256 + threadIdx.x;
  if (n < NN) offs[n] += bsum[blockIdx.x];
  if (n == 0) offs[NN] = EE;
}

// ---------------- CSR scatter: (src, dinv[src]) per edge ----------------
__global__ void k_scatter(const int* __restrict__ ei, const int* __restrict__ offs,
                          int* __restrict__ cursor, const float* __restrict__ dinv,
                          int2* __restrict__ csr){
  int e = blockIdx.x*256 + threadIdx.x;
  if (e >= EE) return;
  int s = ei[e], d = ei[EE + e];
  int pos = offs[d] + atomicAdd(&cursor[d], 1);
  csr[pos] = make_int2(s, __float_as_int(dinv[s]));
}

// ---------------- aggregation: agg[n] = dinv[n]*(sum h[s]*dinv[s] + h[n]*dinv[n]) + b
//                 fused BN-stat partials (sum, sumsq per channel) ----------------
__global__ void __launch_bounds__(256)
k_agg(const float* __restrict__ h, const int2* __restrict__ csr,
      const int* __restrict__ offs, const float* __restrict__ dinv,
      const float* __restrict__ bias, float* __restrict__ agg,
      float* __restrict__ bns){
  const int wib  = threadIdx.x >> 6;   // wave in block (0..3)
  const int lane = threadIdx.x & 63;
  const int gw = blockIdx.x*4 + wib;   // wave per node
  const int nw = gridDim.x*4;
  const int c0 = lane*2;               // 2 channels per lane (float2)
  const float2 b2 = *(const float2*)&bias[c0];
  float sx=0.f, sy=0.f, qx=0.f, qy=0.f;
  for (int n = gw; n < NN; n += nw){
    const float dn = dinv[n];
    float2 hv = *(const float2*)&h[(size_t)n*HD + c0];
    float ax = hv.x*dn, ay = hv.y*dn;  // self-loop term (dinv[n] factored outside)
    const int b0 = offs[n], b1 = offs[n+1];
    for (int e = b0; e < b1; ++e){
      int2 p = csr[e];
      const float w = __int_as_float(p.y);
      float2 hs = *(const float2*)&h[(size_t)p.x*HD + c0];
      ax = fmaf(hs.x, w, ax);
      ay = fmaf(hs.y, w, ay);
    }
    const float ox = fmaf(ax, dn, b2.x);
    const float oy = fmaf(ay, dn, b2.y);
    *(float2*)&agg[(size_t)n*HD + c0] = make_float2(ox, oy);
    sx += ox; sy += oy; qx += ox*ox; qy += oy*oy;
  }
  __shared__ float red[4][64][4];
  red[wib][lane][0]=sx; red[wib][lane][1]=sy; red[wib][lane][2]=qx; red[wib][lane][3]=qy;
  __syncthreads();
  if (wib == 0){
    float a0=0.f,a1=0.f,a2=0.f,a3=0.f;
    #pragma unroll
    for (int w=0; w<4; ++w){
      a0+=red[w][lane][0]; a1+=red[w][lane][1]; a2+=red[w][lane][2]; a3+=red[w][lane][3];
    }
    atomicAdd(&bns[c0  ],    a0);
    atomicAdd(&bns[c0+1],    a1);
    atomicAdd(&bns[HD+c0  ], a2);
    atomicAdd(&bns[HD+c0+1], a3);
  }
}

// ---------------- BN finalize: scale/shift per channel ----------------
__global__ void k_bnfin(const float* __restrict__ bns, const float* __restrict__ g,
                        const float* __restrict__ be, float* __restrict__ scale,
                        float* __restrict__ shift){
  int c = threadIdx.x;
  float m = bns[c] * (1.0f/NN);
  float v = bns[HD+c] * (1.0f/NN) - m*m;
  float sc = g[c] * rsqrtf(v + BNEPS);
  scale[c] = sc;
  shift[c] = be[c] - m*sc;
}

// ---------------- node-row GEMM: OUT = f(A) @ W  (128x128 W)
// MODE 0: f = identity (layer-1 input x)
// MODE 1: f = relu(bn(A));        also writes f(A) to HOUT (residual save)
// MODE 2: f = relu(bn(A)) + res;  also writes f(A) to HOUT ----------------
template<int MODE>
__global__ void __launch_bounds__(256)
k_rowgemm(const float* __restrict__ A, const float* __restrict__ res,
          const float* __restrict__ W, const float* __restrict__ scale,
          const float* __restrict__ shift,
          float* __restrict__ OUT, float* __restrict__ HOUT){
  __shared__ float Wl[32*128];   // W chunk, rows kk..kk+31
  __shared__ float At[32*68];    // A chunk transposed [k][node], pad 68
  const int tid = threadIdx.x;
  const int n0 = blockIdx.x*64;
  const int tx = tid & 31;       // output-channel group (4 ch)
  const int ty = tid >> 5;       // node group (8 nodes)
  float4 acc[8];
  #pragma unroll
  for (int i=0;i<8;i++) acc[i] = make_float4(0.f,0.f,0.f,0.f);

  for (int kk=0; kk<128; kk+=32){
    #pragma unroll
    for (int p=0;p<4;p++){
      int idx = tid*4 + p*1024;
      *(float4*)&Wl[idx] = *(const float4*)&W[kk*128 + idx];
    }
    #pragma unroll
    for (int p=0;p<2;p++){
      int idx = tid*4 + p*1024;   // 0..2047
      int r = idx >> 5;           // node 0..63
      int c = idx & 31;           // k-col, step 4
      int n = n0 + r;
      float4 v = make_float4(0.f,0.f,0.f,0.f);
      if (n < NN){
        v = *(const float4*)&A[(size_t)n*HD + kk + c];
        if (MODE >= 1){
          const float4 sc = *(const float4*)&scale[kk+c];
          const float4 sh = *(const float4*)&shift[kk+c];
          v.x = fmaxf(fmaf(v.x, sc.x, sh.x), 0.f);
          v.y = fmaxf(fmaf(v.y, sc.y, sh.y), 0.f);
          v.z = fmaxf(fmaf(v.z, sc.z, sh.z), 0.f);
          v.w = fmaxf(fmaf(v.w, sc.w, sh.w), 0.f);
          if (MODE == 2){
            const float4 rv = *(const float4*)&res[(size_t)n*HD + kk + c];
            v.x += rv.x; v.y += rv.y; v.z += rv.z; v.w += rv.w;
          }
          *(float4*)&HOUT[(size_t)n*HD + kk + c] = v;
        }
      }
      At[(c+0)*68 + r] = v.x;
      At[(c+1)*68 + r] = v.y;
      At[(c+2)*68 + r] = v.z;
      At[(c+3)*68 + r] = v.w;
    }
    __syncthreads();
    #pragma unroll 8
    for (int k=0;k<32;k++){
      const float4 b  = *(const float4*)&Wl[k*128 + tx*4];
      const float4 a0 = *(const float4*)&At[k*68 + ty*8];
      const float4 a1 = *(const float4*)&At[k*68 + ty*8 + 4];
      const float av[8] = {a0.x,a0.y,a0.z,a0.w,a1.x,a1.y,a1.z,a1.w};
      #pragma unroll
      for (int i=0;i<8;i++){
        acc[i].x = fmaf(av[i], b.x, acc[i].x);
        acc[i].y = fmaf(av[i], b.y, acc[i].y);
        acc[i].z = fmaf(av[i], b.z, acc[i].z);
        acc[i].w = fmaf(av[i], b.w, acc[i].w);
      }
    }
    __syncthreads();
  }
  #pragma unroll
  for (int i=0;i<8;i++){
    int n = n0 + ty*8 + i;
    if (n < NN) *(float4*)&OUT[(size_t)n*HD + tx*4] = acc[i];
  }
}

// ---------------- layer-3 epilogue + segment pooling (batch is sorted) ----------------
__global__ void __launch_bounds__(128)
k_pool(const float* __restrict__ agg, const float* __restrict__ scale,
       const float* __restrict__ shift, const float* __restrict__ h2,
       const int* __restrict__ batch, float* __restrict__ pool,
       float* __restrict__ pcnt){
  const int t = threadIdx.x;
  const int n0 = blockIdx.x*128;
  const float sc = scale[t], sh = shift[t];
  float racc = 0.f;
  int cur = -1, runlen = 0;
  for (int i=0;i<128;i++){
    int n = n0 + i;
    if (n >= NN) break;
    int g = batch[n];
    float v = fmaxf(fmaf(agg[(size_t)n*HD + t], sc, sh), 0.f) + h2[(size_t)n*HD + t];
    if (g != cur){
      if (cur >= 0){
        atomicAdd(&pool[cur*HD + t], racc);
        if (t == 0) atomicAdd(&pcnt[cur], (float)runlen);
      }
      cur = g; racc = 0.f; runlen = 0;
    }
    racc += v; runlen++;
  }
  if (cur >= 0){
    atomicAdd(&pool[cur*HD + t], racc);
    if (t == 0) atomicAdd(&pcnt[cur], (float)runlen);
  }
}

// ---------------- MLP head: relu([sum,mean] @ Wm1 + bm1) @ Wm2 + bm2 ----------------
__global__ void __launch_bounds__(128)
k_mlp(const float* __restrict__ pool, const float* __restrict__ pcnt,
      const float* __restrict__ Wm1, const float* __restrict__ bm1,
      const float* __restrict__ Wm2, const float* __restrict__ bm2,
      float* __restrict__ out){
  __shared__ float z[2*HD];
  __shared__ float red[HD];
  const int g = blockIdx.x, t = threadIdx.x;
  float s = pool[g*HD + t];
  float c = fmaxf(pcnt[g], 1.0f);
  z[t] = s; z[HD + t] = s / c;
  __syncthreads();
  float acc = bm1[t];
  for (int i=0;i<2*HD;i++) acc = fmaf(z[i], Wm1[i*HD + t], acc);
  acc = fmaxf(acc, 0.f);
  red[t] = acc * Wm2[t];
  __syncthreads();
  for (int off=64; off>0; off>>=1){
    if (t < off) red[t] += red[t+off];
    __syncthreads();
  }
  if (t == 0) out[g] = red[0] + bm2[0];
}

extern "C" void kernel_launch(void* const* d_in, const int* in_sizes, int n_in,
                              void* d_out, int out_size, void* d_ws, size_t ws_size,
                              hipStream_t stream){
  const float* x   = (const float*)d_in[0];
  const int*  ei   = (const int*)d_in[1];
  const int*  batch= (const int*)d_in[2];
  const float* W1  = (const float*)d_in[3];
  const float* b1  = (const float*)d_in[4];
  const float* W2  = (const float*)d_in[5];
  const float* b2  = (const float*)d_in[6];
  const float* W3  = (const float*)d_in[7];
  const float* b3  = (const float*)d_in[8];
  const float* g1  = (const float*)d_in[9];
  const float* be1 = (const float*)d_in[10];
  const float* g2  = (const float*)d_in[11];
  const float* be2 = (const float*)d_in[12];
  const float* g3  = (const float*)d_in[13];
  const float* be3 = (const float*)d_in[14];
  const float* Wm1 = (const float*)d_in[15];
  const float* bm1 = (const float*)d_in[16];
  const float* Wm2 = (const float*)d_in[17];
  const float* bm2 = (const float*)d_in[18];
  float* out = (float*)d_out;
  (void)in_sizes; (void)n_in; (void)out_size; (void)ws_size;

  // ---- workspace bump allocator (zeroed region first) ----
  char* p = (char*)d_ws;
  auto alloc = [&](size_t bytes)->void*{
    void* r = (void*)p;
    p += (bytes + 511) & ~(size_t)511;
    return r;
  };
  int*   deg    = (int*)  alloc(NN*sizeof(int));       // zeroed
  int*   cursor = (int*)  alloc(NN*sizeof(int));       // zeroed
  float* bns    = (float*)alloc(3*2*HD*sizeof(float)); // zeroed
  float* pool   = (float*)alloc(GG*HD*sizeof(float));  // zeroed
  float* pcnt   = (float*)alloc(GG*sizeof(float));     // zeroed
  size_t zbytes = (size_t)(p - (char*)d_ws);
  int*   offs   = (int*)  alloc((NN+1)*sizeof(int));
  int*   bsum   = (int*)  alloc(512*sizeof(int));
  float* dinv   = (float*)alloc(NN*sizeof(float));
  float* scale  = (float*)alloc(3*HD*sizeof(float));
  float* shift  = (float*)alloc(3*HD*sizeof(float));
  int2*  csr    = (int2*) alloc((size_t)EE*sizeof(int2));
  float* hh     = (float*)alloc((size_t)NN*HD*sizeof(float));
  float* agg    = (float*)alloc((size_t)NN*HD*sizeof(float));
  float* hres   = (float*)alloc((size_t)NN*HD*sizeof(float));

  hipMemsetAsync(d_ws, 0, zbytes, stream);

  // ---- CSR build ----
  k_hist   <<<(EE+255)/256, 256, 0, stream>>>(ei, deg);
  k_dinv   <<<NB, 256, 0, stream>>>(deg, dinv);
  k_scanA  <<<NB, 256, 0, stream>>>(deg, offs, bsum);
  k_scanB  <<<1, 512, 0, stream>>>(bsum);
  k_scanC  <<<NB, 256, 0, stream>>>(offs, bsum);
  k_scatter<<<(EE+255)/256, 256, 0, stream>>>(ei, offs, cursor, dinv, csr);

  const int GB = (NN+63)/64;
  // ---- layer 1 ----
  k_rowgemm<0><<<GB, 256, 0, stream>>>(x,   nullptr, W1, nullptr,    nullptr,    hh, nullptr);
  k_agg       <<<2048, 256, 0, stream>>>(hh, csr, offs, dinv, b1, agg, bns);
  k_bnfin     <<<1, 128, 0, stream>>>(bns,        g1, be1, scale,      shift);
  // ---- layer 2 ----
  k_rowgemm<1><<<GB, 256, 0, stream>>>(agg, nullptr, W2, scale,      shift,      hh, hres);
  k_agg       <<<2048, 256, 0, stream>>>(hh, csr, offs, dinv, b2, agg, bns + 2*HD);
  k_bnfin     <<<1, 128, 0, stream>>>(bns + 2*HD, g2, be2, scale+HD,   shift+HD);
  // ---- layer 3 ----
  k_rowgemm<2><<<GB, 256, 0, stream>>>(agg, hres,    W3, scale+HD,   shift+HD,   hh, hres);
  k_agg       <<<2048, 256, 0, stream>>>(hh, csr, offs, dinv, b3, agg, bns + 4*HD);
  k_bnfin     <<<1, 128, 0, stream>>>(bns + 4*HD, g3, be3, scale+2*HD, shift+2*HD);

  // ---- pooling + MLP ----
  k_pool<<<(NN+127)/128, 128, 0, stream>>>(agg, scale+2*HD, shift+2*HD, hres, batch, pool, pcnt);
  k_mlp <<<GG, 128, 0, stream>>>(pool, pcnt, Wm1, bm1, Wm2, bm2, out);
}